// Round 1
// baseline (4560.170 us; speedup 1.0000x reference)
//
#include <hip/hip_runtime.h>

// Problem constants (from reference): M=512, N=2048, B=4, L=20, H density 0.02.
#define MM 512
#define NN 2048
#define BB 4
#define LL 20
#define MAXDEG 128   // row weight ~41, sigma ~6.3 -> 128 is ~13 sigma safe
#define MAXCOL 64    // col weight ~10, sigma ~3.2 -> 64 is ~17 sigma safe
#define EPSV 1e-6f

// ---------------- workspace layout (bytes) ----------------
// 0       : row_deg   int[512]            (2048)
// 2048    : row_cols  int[512*128]        (262144)
// 264192  : row_offf  float[512]          (2048)
// 266240  : col_cnt   int[2048]           (8192)
// 274432  : col_edges int[2048*64]        (524288)
// 798720  : msgs      float[4*512*128]    (1048576)
// total ~1.85 MB

// One wave per row: ballot-compact the 0/1 H row into sorted column list.
__global__ __launch_bounds__(64)
void build_rows(const float* __restrict__ H, int* __restrict__ row_deg,
                int* __restrict__ row_cols, float* __restrict__ row_offf) {
    int i = blockIdx.x;
    int lane = threadIdx.x;            // 0..63
    const float* hrow = H + (size_t)i * NN;
    int base = 0;
    for (int chunk = 0; chunk < NN / 64; ++chunk) {
        int c = chunk * 64 + lane;
        bool pred = hrow[c] != 0.0f;
        unsigned long long mask = __ballot(pred);
        int before = __popcll(mask & ((1ull << lane) - 1ull));
        if (pred) {
            int idx = base + before;
            if (idx < MAXDEG) row_cols[i * MAXDEG + idx] = c;
        }
        base += __popcll(mask);
    }
    if (lane == 0) {
        int d = base < MAXDEG ? base : MAXDEG;
        row_deg[i] = d;
        // off-support entries each contribute clip(1.0) = 1-eps to the row product
        row_offf[i] = powf(1.0f - EPSV, (float)(NN - base));
    }
}

// Transpose: for each valid edge slot, append edge id to its column's list.
__global__ __launch_bounds__(256)
void build_cols(const int* __restrict__ row_deg, const int* __restrict__ row_cols,
                int* __restrict__ col_cnt, int* __restrict__ col_edges) {
    int g = blockIdx.x * blockDim.x + threadIdx.x;   // 0 .. 512*128-1
    int i = g >> 7;
    int k = g & (MAXDEG - 1);
    if (k < row_deg[i]) {
        int j = row_cols[g];
        int pos = atomicAdd(&col_cnt[j], 1);
        if (pos < MAXCOL) col_edges[j * MAXCOL + pos] = g;
    }
}

__device__ __forceinline__ float clip_d(float d) {
    if (d == 0.0f) d = 1.0f;                          // reference: where(d==0, 1, d)
    return fminf(fmaxf(d, -1.0f + EPSV), 1.0f - EPSV);
}

// One block per batch element. 1024 threads = 16 waves.
__global__ __launch_bounds__(1024)
void nbp_main(const int* __restrict__ synd, const int* __restrict__ errs,
              const float* __restrict__ llrs,
              const float* __restrict__ w_de,  const float* __restrict__ w_llr,
              const float* __restrict__ mw_de, const float* __restrict__ mw_llr,
              const float* __restrict__ rhos,  const float* __restrict__ resw,
              const int* __restrict__ row_deg, const int* __restrict__ row_cols,
              const float* __restrict__ row_offf,
              const int* __restrict__ col_cnt, const int* __restrict__ col_edges,
              float* __restrict__ msgs, float* __restrict__ out) {
    __shared__ float colsum[NN];
    __shared__ float rho_n[LL];
    __shared__ float red[16];

    const int b    = blockIdx.x;
    const int tid  = threadIdx.x;
    const int lane = tid & 63;
    const int wave = tid >> 6;

    if (tid == 0) {   // softmax over rhos (L=20, trivial)
        float mx = -1e30f;
        for (int l = 0; l < LL; ++l) mx = fmaxf(mx, rhos[l]);
        float s = 0.0f;
        for (int l = 0; l < LL; ++l) { float e = expf(rhos[l] - mx); rho_n[l] = e; s += e; }
        for (int l = 0; l < LL; ++l) rho_n[l] /= s;
    }
    __syncthreads();

    float* msg_b        = msgs + (size_t)b * (MM * MAXDEG);
    const int* synd_b   = synd + b * MM;      // (B,M,1) flat
    const int* err_b    = errs + b * NN;

    float loss = 0.0f;

    for (int l = 0; l < LL; ++l) {
        const float* wde_l   = w_de  + (size_t)l * MM * NN;
        const float* mwde_l  = mw_de + (size_t)l * MM * NN;
        const float* wllr_l  = w_llr  + l * NN;
        const float* mwllr_l = mw_llr + l * NN;
        const float  rw      = resw[l];

        // ---- P1: per-column weighted sums of incoming messages ----
        for (int j = tid; j < NN; j += 1024) {
            float cs = 0.0f;
            const int cnt = col_cnt[j];
            const int* ce = col_edges + j * MAXCOL;
            for (int c = 0; c < cnt; ++c) {
                int e = ce[c];
                cs += msg_b[e] * wde_l[(e >> 7) * NN + j];
            }
            colsum[j] = cs;
        }
        __syncthreads();

        // ---- P2: row (check-node) tanh-product update, one wave per row ----
        for (int i = wave; i < MM; i += 16) {
            const int deg = row_deg[i];
            float d0 = 1.0f, d1 = 1.0f, m0 = 0.0f, m1 = 0.0f;
            const bool v0 = lane < deg;
            const bool v1 = (lane + 64) < deg;
            if (v0) {
                int e = i * MAXDEG + lane;
                int j = row_cols[e];
                m0 = msg_b[e];
                float en = llrs[j] * wllr_l[j] + colsum[j] - m0;
                d0 = clip_d(tanhf(0.5f * en));
            }
            if (v1) {
                int e = i * MAXDEG + lane + 64;
                int j = row_cols[e];
                m1 = msg_b[e];
                float en = llrs[j] * wllr_l[j] + colsum[j] - m1;
                d1 = clip_d(tanhf(0.5f * en));
            }
            float p = d0 * d1;
            #pragma unroll
            for (int off = 1; off < 64; off <<= 1) p *= __shfl_xor(p, off);
            const float rowprod = p * row_offf[i];
            const float sgn = 1.0f - 2.0f * (float)synd_b[i];
            if (v0) msg_b[i * MAXDEG + lane]      = 2.0f * atanhf(rowprod / d0) * sgn + rw * m0;
            if (v1) msg_b[i * MAXDEG + lane + 64] = 2.0f * atanhf(rowprod / d1) * sgn + rw * m1;
        }
        __syncthreads();

        // ---- P3: beliefs + weighted BCE loss ----
        const float rho = rho_n[l];
        for (int j = tid; j < NN; j += 1024) {
            float bel = llrs[j] * mwllr_l[j];
            const int cnt = col_cnt[j];
            const int* ce = col_edges + j * MAXCOL;
            for (int c = 0; c < cnt; ++c) {
                int e = ce[c];
                bel += msg_b[e] * mwde_l[(e >> 7) * NN + j];
            }
            float sp = fmaxf(bel, 0.0f) + log1pf(expf(-fabsf(bel)));  // softplus
            loss += rho * (sp - (1.0f - (float)err_b[j]) * bel);
        }
        // no extra sync needed: next P1 only reads msgs / writes colsum, and the
        // sync after next P1 orders it against everyone's P3 completion.
    }

    // ---- block reduction of loss, then one global atomic ----
    #pragma unroll
    for (int off = 32; off > 0; off >>= 1) loss += __shfl_down(loss, off);
    if (lane == 0) red[wave] = loss;
    __syncthreads();
    if (wave == 0) {
        float v = (lane < 16) ? red[lane] : 0.0f;
        #pragma unroll
        for (int off = 8; off > 0; off >>= 1) v += __shfl_down(v, off);
        if (lane == 0) atomicAdd(out, v * 0.25f);   // / batch
    }
}

extern "C" void kernel_launch(void* const* d_in, const int* in_sizes, int n_in,
                              void* d_out, int out_size, void* d_ws, size_t ws_size,
                              hipStream_t stream) {
    const int*   synd  = (const int*)  d_in[0];   // syndromes (B,M,1) int32
    const int*   errs  = (const int*)  d_in[1];   // errors (B,N) int32
    const float* H     = (const float*)d_in[2];   // (M,N)
    const float* llrs  = (const float*)d_in[3];   // (N,)
    const float* w_de  = (const float*)d_in[4];   // (L,M,N)
    const float* w_llr = (const float*)d_in[5];   // (L,N)
    const float* mw_de = (const float*)d_in[6];   // (L,M,N)
    const float* mw_llr= (const float*)d_in[7];   // (L,N)
    const float* rhos  = (const float*)d_in[8];   // (L,)
    const float* resw  = (const float*)d_in[9];   // (L,)

    char* ws = (char*)d_ws;
    int*   row_deg   = (int*)  (ws + 0);
    int*   row_cols  = (int*)  (ws + 2048);
    float* row_offf  = (float*)(ws + 264192);
    int*   col_cnt   = (int*)  (ws + 266240);
    int*   col_edges = (int*)  (ws + 274432);
    float* msgs      = (float*)(ws + 798720);
    float* out       = (float*)d_out;

    // ws/out are poisoned 0xAA before every timed launch — zero what we need.
    hipMemsetAsync(col_cnt, 0, NN * sizeof(int), stream);
    hipMemsetAsync(msgs, 0, (size_t)BB * MM * MAXDEG * sizeof(float), stream);
    hipMemsetAsync(d_out, 0, sizeof(float), stream);

    build_rows<<<MM, 64, 0, stream>>>(H, row_deg, row_cols, row_offf);
    build_cols<<<(MM * MAXDEG) / 256, 256, 0, stream>>>(row_deg, row_cols, col_cnt, col_edges);
    nbp_main<<<BB, 1024, 0, stream>>>(synd, errs, llrs, w_de, w_llr, mw_de, mw_llr,
                                      rhos, resw, row_deg, row_cols, row_offf,
                                      col_cnt, col_edges, msgs, out);
}

// Round 2
// 2186.218 us; speedup vs baseline: 2.0859x; 2.0859x over previous
//
#include <hip/hip_runtime.h>

// M=512, N=2048, B=4, L=20, H density 0.02 (row weight ~41, col weight ~10).
#define MM 512
#define NN 2048
#define BB 4
#define LL 20
#define MAXDEG 128      // per-row cap (~13 sigma)
#define MAXCOL 64       // per-col cap (~17 sigma)
#define EMAX  24576     // total edges ~20973 expected, sd ~143 -> safe cap
#define EPSV 1e-6f

// ---------------- workspace layout (bytes) ----------------
#define WS_ROW_DEG   0          // int[512]
#define WS_ROW_PAD   2048       // int[512*128]
#define WS_ROW_OFFF  264192     // float[512]
#define WS_ROW_PTR   266240     // int[513] (padded)
#define WS_COL_CNT   268416     // int[2048]
#define WS_COL_EDG   276608     // int[2048*64]
#define WS_EDGE_ROW  800896     // int[EMAX]
#define WS_EDGE_COL  899200     // int[EMAX]
#define WS_WDE_G     997504     // float[L*EMAX]
#define WS_MWDE_G    2963584    // float[L*EMAX]
#define WS_LLRW      4929664    // float[L*N]
#define WS_MLLRW     5093504    // float[L*N]
#define WS_MSGS      5257344    // float[B*EMAX]
// total ~5.65 MB

// ---- k1: one wave per row, ballot-compact H row into padded list ----
__global__ __launch_bounds__(64)
void build_rows(const float* __restrict__ H, int* __restrict__ row_deg,
                int* __restrict__ row_pad, float* __restrict__ row_offf) {
    int i = blockIdx.x, lane = threadIdx.x;
    const float* hrow = H + (size_t)i * NN;
    int base = 0;
    for (int chunk = 0; chunk < NN / 64; ++chunk) {
        int c = chunk * 64 + lane;
        bool pred = hrow[c] != 0.0f;
        unsigned long long mask = __ballot(pred);
        int before = __popcll(mask & ((1ull << lane) - 1ull));
        if (pred) {
            int idx = base + before;
            if (idx < MAXDEG) row_pad[i * MAXDEG + idx] = c;
        }
        base += __popcll(mask);
    }
    if (lane == 0) {
        row_deg[i] = base < MAXDEG ? base : MAXDEG;
        // off-support entries contribute clip(1.0)=1-eps each to the row product
        row_offf[i] = powf(1.0f - EPSV, (float)(NN - base));
    }
}

// ---- k2: exclusive prefix sum of row degrees (single block) ----
__global__ __launch_bounds__(512)
void scan_rows(const int* __restrict__ row_deg, int* __restrict__ row_ptr) {
    __shared__ int tmp[512];
    int t = threadIdx.x;
    tmp[t] = row_deg[t];
    __syncthreads();
    for (int off = 1; off < 512; off <<= 1) {
        int v = (t >= off) ? tmp[t - off] : 0;
        __syncthreads();
        tmp[t] += v;
        __syncthreads();
    }
    if (t == 0) row_ptr[0] = 0;
    row_ptr[t + 1] = tmp[t];
}

// ---- k3: fill compact CSR edge arrays + column lists ----
__global__ __launch_bounds__(64)
void fill_edges(const int* __restrict__ row_deg, const int* __restrict__ row_pad,
                const int* __restrict__ row_ptr, int* __restrict__ edge_row,
                int* __restrict__ edge_col, int* __restrict__ col_cnt,
                int* __restrict__ col_edges) {
    int i = blockIdx.x, lane = threadIdx.x;
    int deg = row_deg[i], base = row_ptr[i];
    for (int k = lane; k < deg; k += 64) {
        int j = row_pad[i * MAXDEG + k];
        int e = base + k;
        edge_row[e] = i;
        edge_col[e] = j;
        int pos = atomicAdd(&col_cnt[j], 1);
        if (pos < MAXCOL) col_edges[j * MAXCOL + pos] = e;
    }
}

// ---- k4: massively parallel gather of dense weights at support ----
__global__ __launch_bounds__(256)
void gather_weights(const float* __restrict__ w_de, const float* __restrict__ mw_de,
                    const int* __restrict__ edge_row, const int* __restrict__ edge_col,
                    const int* __restrict__ row_ptr,
                    float* __restrict__ wde_g, float* __restrict__ mwde_g) {
    int idx = blockIdx.x * blockDim.x + threadIdx.x;   // 0 .. L*EMAX-1
    int l = idx / EMAX, e = idx - l * EMAX;
    if (e < row_ptr[MM]) {
        size_t src = (size_t)l * MM * NN + (size_t)edge_row[e] * NN + edge_col[e];
        wde_g[idx]  = w_de[src];
        mwde_g[idx] = mw_de[src];
    }
}

// ---- k5: pre-multiply llrs into per-layer llr weights ----
__global__ __launch_bounds__(256)
void gather_llr(const float* __restrict__ llrs, const float* __restrict__ w_llr,
                const float* __restrict__ mw_llr,
                float* __restrict__ llrw, float* __restrict__ mllrw) {
    int idx = blockIdx.x * blockDim.x + threadIdx.x;   // 0 .. L*N-1
    int j = idx & (NN - 1);
    llrw[idx]  = llrs[j] * w_llr[idx];
    mllrw[idx] = llrs[j] * mw_llr[idx];
}

__device__ __forceinline__ float clip_d(float d) {
    if (d == 0.0f) d = 1.0f;                          // reference: where(d==0, 1, d)
    return fminf(fmaxf(d, -1.0f + EPSV), 1.0f - EPSV);
}

// ---- main serial BP kernel: one block per batch, compact edge-space ----
__global__ __launch_bounds__(1024)
void nbp_main(const int* __restrict__ synd, const int* __restrict__ errs,
              const float* __restrict__ rhos, const float* __restrict__ resw,
              const int* __restrict__ row_ptr, const float* __restrict__ row_offf,
              const int* __restrict__ edge_col,
              const int* __restrict__ col_cnt, const int* __restrict__ col_edges,
              const float* __restrict__ wde_g, const float* __restrict__ mwde_g,
              const float* __restrict__ llrw, const float* __restrict__ mllrw,
              float* __restrict__ msgs, float* __restrict__ out) {
    __shared__ float colsum[NN];
    __shared__ float rho_n[LL];
    __shared__ float red[16];

    const int b = blockIdx.x, tid = threadIdx.x;
    const int lane = tid & 63, wave = tid >> 6;

    if (tid == 0) {   // softmax over rhos (L=20)
        float mx = -1e30f;
        for (int l = 0; l < LL; ++l) mx = fmaxf(mx, rhos[l]);
        float s = 0.0f;
        for (int l = 0; l < LL; ++l) { float e = __expf(rhos[l] - mx); rho_n[l] = e; s += e; }
        for (int l = 0; l < LL; ++l) rho_n[l] /= s;
    }
    __syncthreads();

    float* msg_b      = msgs + (size_t)b * EMAX;
    const int* synd_b = synd + b * MM;
    const int* err_b  = errs + b * NN;

    float loss = 0.0f;

    for (int l = 0; l < LL; ++l) {
        const float* wde_l   = wde_g  + (size_t)l * EMAX;
        const float* mwde_l  = mwde_g + (size_t)l * EMAX;
        const float* llrw_l  = llrw   + l * NN;
        const float* mllrw_l = mllrw  + l * NN;
        const float  rw      = resw[l];

        // ---- P1: per-column weighted sums of incoming messages ----
        for (int j = tid; j < NN; j += 1024) {
            float cs = 0.0f;
            const int cnt = col_cnt[j];
            const int* ce = col_edges + j * MAXCOL;
            for (int c = 0; c < cnt; ++c) {
                int e = ce[c];
                cs += msg_b[e] * wde_l[e];
            }
            colsum[j] = cs;
        }
        __syncthreads();

        // ---- P2: row (check-node) tanh-product update, one wave per row ----
        for (int i = wave; i < MM; i += 16) {
            const int base = row_ptr[i];
            const int deg  = row_ptr[i + 1] - base;
            const int e0 = base + lane, e1 = base + lane + 64;
            const bool v0 = lane < deg;
            const bool v1 = (lane + 64) < deg;
            float d0 = 1.0f, d1 = 1.0f, m0 = 0.0f, m1 = 0.0f;
            if (v0) {
                int j = edge_col[e0];
                m0 = msg_b[e0];
                float en = llrw_l[j] + colsum[j] - m0;
                float t = __expf(en);                     // tanh(en/2) = 1 - 2/(e^en+1)
                d0 = clip_d(1.0f - 2.0f / (t + 1.0f));
            }
            if (v1) {
                int j = edge_col[e1];
                m1 = msg_b[e1];
                float en = llrw_l[j] + colsum[j] - m1;
                float t = __expf(en);
                d1 = clip_d(1.0f - 2.0f / (t + 1.0f));
            }
            float p = d0 * d1;
            #pragma unroll
            for (int off = 1; off < 64; off <<= 1) p *= __shfl_xor(p, off);
            const float rowprod = p * row_offf[i];
            const float sgn = 1.0f - 2.0f * (float)synd_b[i];
            if (v0) {                                     // 2*atanh(r) = log((1+r)/(1-r))
                float r = rowprod / d0;
                msg_b[e0] = sgn * __logf((1.0f + r) / (1.0f - r)) + rw * m0;
            }
            if (v1) {
                float r = rowprod / d1;
                msg_b[e1] = sgn * __logf((1.0f + r) / (1.0f - r)) + rw * m1;
            }
        }
        __syncthreads();

        // ---- P3: beliefs + weighted BCE loss ----
        const float rho = rho_n[l];
        for (int j = tid; j < NN; j += 1024) {
            float bel = mllrw_l[j];
            const int cnt = col_cnt[j];
            const int* ce = col_edges + j * MAXCOL;
            for (int c = 0; c < cnt; ++c) {
                int e = ce[c];
                bel += msg_b[e] * mwde_l[e];
            }
            float sp = fmaxf(bel, 0.0f) + log1pf(__expf(-fabsf(bel)));
            loss += rho * (sp - (1.0f - (float)err_b[j]) * bel);
        }
        // next P1 only reads msgs / writes colsum; its trailing sync orders P3.
    }

    #pragma unroll
    for (int off = 32; off > 0; off >>= 1) loss += __shfl_down(loss, off);
    if (lane == 0) red[wave] = loss;
    __syncthreads();
    if (wave == 0) {
        float v = (lane < 16) ? red[lane] : 0.0f;
        #pragma unroll
        for (int off = 8; off > 0; off >>= 1) v += __shfl_down(v, off);
        if (lane == 0) atomicAdd(out, v * 0.25f);
    }
}

extern "C" void kernel_launch(void* const* d_in, const int* in_sizes, int n_in,
                              void* d_out, int out_size, void* d_ws, size_t ws_size,
                              hipStream_t stream) {
    const int*   synd  = (const int*)  d_in[0];
    const int*   errs  = (const int*)  d_in[1];
    const float* H     = (const float*)d_in[2];
    const float* llrs  = (const float*)d_in[3];
    const float* w_de  = (const float*)d_in[4];
    const float* w_llr = (const float*)d_in[5];
    const float* mw_de = (const float*)d_in[6];
    const float* mw_llr= (const float*)d_in[7];
    const float* rhos  = (const float*)d_in[8];
    const float* resw  = (const float*)d_in[9];

    char* ws = (char*)d_ws;
    int*   row_deg   = (int*)  (ws + WS_ROW_DEG);
    int*   row_pad   = (int*)  (ws + WS_ROW_PAD);
    float* row_offf  = (float*)(ws + WS_ROW_OFFF);
    int*   row_ptr   = (int*)  (ws + WS_ROW_PTR);
    int*   col_cnt   = (int*)  (ws + WS_COL_CNT);
    int*   col_edges = (int*)  (ws + WS_COL_EDG);
    int*   edge_row  = (int*)  (ws + WS_EDGE_ROW);
    int*   edge_col  = (int*)  (ws + WS_EDGE_COL);
    float* wde_g     = (float*)(ws + WS_WDE_G);
    float* mwde_g    = (float*)(ws + WS_MWDE_G);
    float* llrw      = (float*)(ws + WS_LLRW);
    float* mllrw     = (float*)(ws + WS_MLLRW);
    float* msgs      = (float*)(ws + WS_MSGS);
    float* out       = (float*)d_out;

    hipMemsetAsync(col_cnt, 0, NN * sizeof(int), stream);
    hipMemsetAsync(msgs, 0, (size_t)BB * EMAX * sizeof(float), stream);
    hipMemsetAsync(d_out, 0, sizeof(float), stream);

    build_rows<<<MM, 64, 0, stream>>>(H, row_deg, row_pad, row_offf);
    scan_rows<<<1, 512, 0, stream>>>(row_deg, row_ptr);
    fill_edges<<<MM, 64, 0, stream>>>(row_deg, row_pad, row_ptr,
                                      edge_row, edge_col, col_cnt, col_edges);
    gather_weights<<<(LL * EMAX) / 256, 256, 0, stream>>>(w_de, mw_de, edge_row,
                                                          edge_col, row_ptr, wde_g, mwde_g);
    gather_llr<<<(LL * NN) / 256, 256, 0, stream>>>(llrs, w_llr, mw_llr, llrw, mllrw);
    nbp_main<<<BB, 1024, 0, stream>>>(synd, errs, rhos, resw, row_ptr, row_offf,
                                      edge_col, col_cnt, col_edges, wde_g, mwde_g,
                                      llrw, mllrw, msgs, out);
}

// Round 3
// 1560.987 us; speedup vs baseline: 2.9213x; 1.4005x over previous
//
#include <hip/hip_runtime.h>

// M=512, N=2048, B=4, L=20, H density 0.02 (row weight ~41, col weight ~10).
#define MM 512
#define NN 2048
#define BB 4
#define LL 20
#define MAXDEG 128      // per-row cap (~13 sigma)
#define EMAX  24576     // total edges ~20973 expected -> safe cap
#define EPSV 1e-6f

// ---------------- workspace layout (bytes) ----------------
#define WS_ROW_DEG   0          // int[512]
#define WS_ROW_PAD   2048       // int[512*128]
#define WS_ROW_OFFF  264192     // float[512]
#define WS_ROW_PTR   266240     // int[513]
#define WS_EDGE_ROW  268416     // int[EMAX]
#define WS_EDGE_COL  366720     // int[EMAX]
#define WS_WDE_G     465024     // float[L*EMAX]
#define WS_MWDE_G    2431104    // float[L*EMAX]
#define WS_LLRW      4397184    // float[L*N]
#define WS_MLLRW     4561024    // float[L*N]
#define WS_MSGS      4724864    // float[B*EMAX]
#define WS_DG        5118080    // float[B*EMAX]
// total ~5.51 MB

// ---- k1: one wave per row, ballot-compact H row into padded list ----
__global__ __launch_bounds__(64)
void build_rows(const float* __restrict__ H, int* __restrict__ row_deg,
                int* __restrict__ row_pad, float* __restrict__ row_offf) {
    int i = blockIdx.x, lane = threadIdx.x;
    const float* hrow = H + (size_t)i * NN;
    int base = 0;
    for (int chunk = 0; chunk < NN / 64; ++chunk) {
        int c = chunk * 64 + lane;
        bool pred = hrow[c] != 0.0f;
        unsigned long long mask = __ballot(pred);
        int before = __popcll(mask & ((1ull << lane) - 1ull));
        if (pred) {
            int idx = base + before;
            if (idx < MAXDEG) row_pad[i * MAXDEG + idx] = c;
        }
        base += __popcll(mask);
    }
    if (lane == 0) {
        row_deg[i] = base < MAXDEG ? base : MAXDEG;
        // off-support entries contribute clip(1.0)=1-eps each to the row product
        row_offf[i] = powf(1.0f - EPSV, (float)(NN - base));
    }
}

// ---- k2: exclusive prefix sum of row degrees (single block) ----
__global__ __launch_bounds__(512)
void scan_rows(const int* __restrict__ row_deg, int* __restrict__ row_ptr) {
    __shared__ int tmp[512];
    int t = threadIdx.x;
    tmp[t] = row_deg[t];
    __syncthreads();
    for (int off = 1; off < 512; off <<= 1) {
        int v = (t >= off) ? tmp[t - off] : 0;
        __syncthreads();
        tmp[t] += v;
        __syncthreads();
    }
    if (t == 0) row_ptr[0] = 0;
    row_ptr[t + 1] = tmp[t];
}

// ---- k3: fill compact CSR edge arrays ----
__global__ __launch_bounds__(64)
void fill_edges(const int* __restrict__ row_deg, const int* __restrict__ row_pad,
                const int* __restrict__ row_ptr, int* __restrict__ edge_row,
                int* __restrict__ edge_col) {
    int i = blockIdx.x, lane = threadIdx.x;
    int deg = row_deg[i], base = row_ptr[i];
    for (int k = lane; k < deg; k += 64) {
        edge_row[base + k] = i;
        edge_col[base + k] = row_pad[i * MAXDEG + k];
    }
}

// ---- k4: massively parallel gather of dense weights at support ----
__global__ __launch_bounds__(256)
void gather_weights(const float* __restrict__ w_de, const float* __restrict__ mw_de,
                    const int* __restrict__ edge_row, const int* __restrict__ edge_col,
                    const int* __restrict__ row_ptr,
                    float* __restrict__ wde_g, float* __restrict__ mwde_g) {
    int idx = blockIdx.x * blockDim.x + threadIdx.x;   // 0 .. L*EMAX-1
    int l = idx / EMAX, e = idx - l * EMAX;
    if (e < row_ptr[MM]) {
        size_t src = (size_t)l * MM * NN + (size_t)edge_row[e] * NN + edge_col[e];
        wde_g[idx]  = w_de[src];
        mwde_g[idx] = mw_de[src];
    }
}

// ---- k5: pre-multiply llrs into per-layer llr weights ----
__global__ __launch_bounds__(256)
void gather_llr(const float* __restrict__ llrs, const float* __restrict__ w_llr,
                const float* __restrict__ mw_llr,
                float* __restrict__ llrw, float* __restrict__ mllrw) {
    int idx = blockIdx.x * blockDim.x + threadIdx.x;   // 0 .. L*N-1
    int j = idx & (NN - 1);
    llrw[idx]  = llrs[j] * w_llr[idx];
    mllrw[idx] = llrs[j] * mw_llr[idx];
}

// ---- main serial BP kernel: one block per batch, edge-parallel phases ----
__global__ __launch_bounds__(1024)
void nbp_main(const int* __restrict__ synd, const int* __restrict__ errs,
              const float* __restrict__ rhos, const float* __restrict__ resw,
              const int* __restrict__ row_ptr, const float* __restrict__ row_offf,
              const int* __restrict__ edge_row, const int* __restrict__ edge_col,
              const float* __restrict__ wde_g, const float* __restrict__ mwde_g,
              const float* __restrict__ llrw, const float* __restrict__ mllrw,
              float* __restrict__ msgs, float* __restrict__ d_g,
              float* __restrict__ out) {
    __shared__ float colsum_s[NN];   // per-column weighted msg sums
    __shared__ float bel_s[NN];      // beliefs
    __shared__ float llrw_s[NN];     // llrs * w_llr (this layer)
    __shared__ float mllrw_s[NN];    // llrs * mw_llr (this layer)
    __shared__ float w1_s[NN];       // 1 - err (layer-invariant)
    __shared__ float sgn_s[MM];      // (-1)^syndrome (layer-invariant)
    __shared__ float rowprod_s[MM];  // row tanh-product incl. off-support factor
    __shared__ float rho_n[LL];
    __shared__ float red[16];

    const int b = blockIdx.x, tid = threadIdx.x;
    const int lane = tid & 63, wave = tid >> 6;
    const int E = row_ptr[MM];

    float* msg_b = msgs + b * EMAX;
    float* d_b   = d_g  + b * EMAX;

    // ---- init: softmax(rhos), zero msgs, stage layer-invariant LDS ----
    if (tid == 0) {
        float mx = -1e30f;
        for (int l = 0; l < LL; ++l) mx = fmaxf(mx, rhos[l]);
        float s = 0.0f;
        for (int l = 0; l < LL; ++l) { float e = __expf(rhos[l] - mx); rho_n[l] = e; s += e; }
        for (int l = 0; l < LL; ++l) rho_n[l] /= s;
    }
    for (int e = tid; e < E; e += 1024) msg_b[e] = 0.0f;
    for (int j = tid; j < NN; j += 1024) {
        colsum_s[j] = 0.0f;
        w1_s[j] = 1.0f - (float)errs[b * NN + j];
    }
    for (int i = tid; i < MM; i += 1024) sgn_s[i] = 1.0f - 2.0f * (float)synd[b * MM + i];
    __syncthreads();

    float loss = 0.0f;

    for (int l = 0; l < LL; ++l) {
        const float* wde_l   = wde_g  + (size_t)l * EMAX;
        const float* mwde_l  = mwde_g + (size_t)l * EMAX;
        const float  rw      = resw[l];
        const float  rho     = rho_n[l];

        // ---- A: stage per-layer llr weights + edge-parallel colsum scatter ----
        for (int j = tid; j < NN; j += 1024) {
            llrw_s[j]  = llrw [l * NN + j];
            mllrw_s[j] = mllrw[l * NN + j];
        }
        for (int e = tid; e < E; e += 1024) {
            atomicAdd(&colsum_s[edge_col[e]], msg_b[e] * wde_l[e]);
        }
        __syncthreads();

        // ---- B: edge-parallel tanh: d = clip(tanh(en/2)) ----
        for (int e = tid; e < E; e += 1024) {
            int j = edge_col[e];
            float en = llrw_s[j] + colsum_s[j] - msg_b[e];
            float t = __expf(en);                   // tanh(en/2) = 1 - 2/(e^en+1)
            float d = 1.0f - 2.0f / (t + 1.0f);
            if (d == 0.0f) d = 1.0f;                // reference: where(d==0, 1, d)
            d = fminf(fmaxf(d, -1.0f + EPSV), 1.0f - EPSV);
            d_b[e] = d;
        }
        __syncthreads();

        // ---- C: thread-per-row product (tid<512) | belief init (tid>=512) ----
        if (tid < MM) {
            int base = row_ptr[tid];
            int deg  = row_ptr[tid + 1] - base;
            float p0 = 1.0f, p1 = 1.0f;
            int c = 0;
            for (; c + 1 < deg; c += 2) { p0 *= d_b[base + c]; p1 *= d_b[base + c + 1]; }
            if (c < deg) p0 *= d_b[base + c];
            rowprod_s[tid] = p0 * p1 * row_offf[tid];
        } else {
            for (int j = tid - MM; j < NN; j += 1024 - MM) bel_s[j] = mllrw_s[j];
        }
        __syncthreads();

        // ---- D: edge-parallel atanh/writeback fused with belief scatter ----
        for (int e = tid; e < E; e += 1024) {
            int i = edge_row[e], j = edge_col[e];
            float d = d_b[e], m = msg_b[e];
            float r = rowprod_s[i] / d;
            float v = sgn_s[i] * __logf((1.0f + r) / (1.0f - r)) + rw * m;  // 2*atanh
            msg_b[e] = v;
            atomicAdd(&bel_s[j], v * mwde_l[e]);
        }
        __syncthreads();

        // ---- E: column-parallel loss + zero colsum for next layer ----
        for (int j = tid; j < NN; j += 1024) {
            float bel = bel_s[j];
            float sp = fmaxf(bel, 0.0f) + log1pf(__expf(-fabsf(bel)));  // softplus
            loss += rho * (sp - w1_s[j] * bel);
            colsum_s[j] = 0.0f;
        }
        __syncthreads();
    }

    // ---- block reduction of loss, then one global atomic ----
    #pragma unroll
    for (int off = 32; off > 0; off >>= 1) loss += __shfl_down(loss, off);
    if (lane == 0) red[wave] = loss;
    __syncthreads();
    if (wave == 0) {
        float v = (lane < 16) ? red[lane] : 0.0f;
        #pragma unroll
        for (int off = 8; off > 0; off >>= 1) v += __shfl_down(v, off);
        if (lane == 0) atomicAdd(out, v * 0.25f);
    }
}

extern "C" void kernel_launch(void* const* d_in, const int* in_sizes, int n_in,
                              void* d_out, int out_size, void* d_ws, size_t ws_size,
                              hipStream_t stream) {
    const int*   synd  = (const int*)  d_in[0];
    const int*   errs  = (const int*)  d_in[1];
    const float* H     = (const float*)d_in[2];
    const float* llrs  = (const float*)d_in[3];
    const float* w_de  = (const float*)d_in[4];
    const float* w_llr = (const float*)d_in[5];
    const float* mw_de = (const float*)d_in[6];
    const float* mw_llr= (const float*)d_in[7];
    const float* rhos  = (const float*)d_in[8];
    const float* resw  = (const float*)d_in[9];

    char* ws = (char*)d_ws;
    int*   row_deg   = (int*)  (ws + WS_ROW_DEG);
    int*   row_pad   = (int*)  (ws + WS_ROW_PAD);
    float* row_offf  = (float*)(ws + WS_ROW_OFFF);
    int*   row_ptr   = (int*)  (ws + WS_ROW_PTR);
    int*   edge_row  = (int*)  (ws + WS_EDGE_ROW);
    int*   edge_col  = (int*)  (ws + WS_EDGE_COL);
    float* wde_g     = (float*)(ws + WS_WDE_G);
    float* mwde_g    = (float*)(ws + WS_MWDE_G);
    float* llrw      = (float*)(ws + WS_LLRW);
    float* mllrw     = (float*)(ws + WS_MLLRW);
    float* msgs      = (float*)(ws + WS_MSGS);
    float* d_g       = (float*)(ws + WS_DG);
    float* out       = (float*)d_out;

    hipMemsetAsync(d_out, 0, sizeof(float), stream);

    build_rows<<<MM, 64, 0, stream>>>(H, row_deg, row_pad, row_offf);
    scan_rows<<<1, 512, 0, stream>>>(row_deg, row_ptr);
    fill_edges<<<MM, 64, 0, stream>>>(row_deg, row_pad, row_ptr, edge_row, edge_col);
    gather_weights<<<(LL * EMAX) / 256, 256, 0, stream>>>(w_de, mw_de, edge_row,
                                                          edge_col, row_ptr, wde_g, mwde_g);
    gather_llr<<<(LL * NN) / 256, 256, 0, stream>>>(llrs, w_llr, mw_llr, llrw, mllrw);
    nbp_main<<<BB, 1024, 0, stream>>>(synd, errs, rhos, resw, row_ptr, row_offf,
                                      edge_row, edge_col, wde_g, mwde_g,
                                      llrw, mllrw, msgs, d_g, out);
}